// Round 4
// baseline (2270.245 us; speedup 1.0000x reference)
//
#include <hip/hip_runtime.h>
#include <hip/hip_bf16.h>
#include <float.h>

#define NTOK 8192   // B*S
#define H_   2048
#define P_   4096
#define D_   1024
#define I_   1024

#define BM 128
#define BN 128
#define BK 16
#define NCB (P_ / BN)   // 32 column-blocks for the logits GEMM

static __device__ inline void ins2(float& v0, int& i0, float& v1, int& i1, float v, int i) {
    if (v > v0 || (v == v0 && i < i0)) { v1 = v0; i1 = i0; v0 = v; i0 = i; }
    else if (v > v1 || (v == v1 && i < i1)) { v1 = v; i1 = i; }
}

// ---------------------------------------------------------------------------
// fp32 GEMM: epi(A[M,K] @ Bw[K,N] + bias[N])   (all fp32)
// A split: k < ksplit from A, else A2 (both stride lda).
// EPI: 0 bias f32-store | 1 bias+ReLU f32-store
//      3 bias + per-row top-2 over block's 128 cols -> part[tok*NCB + bx]
// 256 thr, 128x128 tile, BK=16, 8x8 micro-tile as 2x2 chunks of 4.
// ---------------------------------------------------------------------------
template<int EPI>
__global__ __launch_bounds__(256) void gemm_f32(
    const float* __restrict__ A, const float* __restrict__ A2, int ksplit, int lda,
    const float* __restrict__ Bw, const float* __restrict__ bias,
    float* __restrict__ C, float4* __restrict__ part, int M, int N, int K)
{
    __shared__ float sA[BK][BM];   // k-major
    __shared__ float sB[BK][BN];

    const int tid = threadIdx.x;
    const int m0 = blockIdx.y * BM;
    const int n0 = blockIdx.x * BN;
    const int tx = tid & 15, ty = tid >> 4;

    const int ar = tid >> 1;            // 0..127 : A row in tile
    const int ak = (tid & 1) * 8;       // 0 or 8 : A k-offset
    const int brow = tid >> 4;          // 0..15  : B k-row
    const int bcol = (tid & 15) * 8;    // 0..120 : B col

    float acc[8][8] = {};

    for (int k0 = 0; k0 < K; k0 += BK) {
        const float* Ab; int kk0;
        if (k0 < ksplit) { Ab = A; kk0 = k0; } else { Ab = A2; kk0 = k0 - ksplit; }
        const float* ap = Ab + (size_t)(m0 + ar) * lda + kk0 + ak;
        float4 a0 = *(const float4*)ap;
        float4 a1 = *(const float4*)(ap + 4);
        const float* bp = Bw + (size_t)(k0 + brow) * N + n0 + bcol;
        float4 b0 = *(const float4*)bp;
        float4 b1 = *(const float4*)(bp + 4);

        __syncthreads();   // previous iteration's compute done before overwrite
        sA[ak + 0][ar] = a0.x; sA[ak + 1][ar] = a0.y;
        sA[ak + 2][ar] = a0.z; sA[ak + 3][ar] = a0.w;
        sA[ak + 4][ar] = a1.x; sA[ak + 5][ar] = a1.y;
        sA[ak + 6][ar] = a1.z; sA[ak + 7][ar] = a1.w;
        *(float4*)&sB[brow][bcol]     = b0;
        *(float4*)&sB[brow][bcol + 4] = b1;
        __syncthreads();

#pragma unroll
        for (int kk = 0; kk < BK; kk++) {
            float4 av0 = *(const float4*)&sA[kk][ty * 4];
            float4 av1 = *(const float4*)&sA[kk][ty * 4 + 64];
            float4 bv0 = *(const float4*)&sB[kk][tx * 4];
            float4 bv1 = *(const float4*)&sB[kk][tx * 4 + 64];
            float a8[8] = {av0.x, av0.y, av0.z, av0.w, av1.x, av1.y, av1.z, av1.w};
            float b8[8] = {bv0.x, bv0.y, bv0.z, bv0.w, bv1.x, bv1.y, bv1.z, bv1.w};
#pragma unroll
            for (int i = 0; i < 8; i++)
#pragma unroll
                for (int j = 0; j < 8; j++) acc[i][j] += a8[i] * b8[j];
        }
    }

    if (EPI == 3) {
#pragma unroll
        for (int i = 0; i < 8; i++) {
            const int row = ty * 4 + (i < 4 ? i : 60 + i);
            float v0 = -FLT_MAX, v1 = -FLT_MAX; int i0 = 0x7fffffff, i1 = 0x7fffffff;
#pragma unroll
            for (int j = 0; j < 8; j++) {
                int n = n0 + tx * 4 + (j < 4 ? j : 60 + j);
                ins2(v0, i0, v1, i1, acc[i][j] + bias[n], n);
            }
#pragma unroll
            for (int msk = 1; msk <= 8; msk <<= 1) {
                float pv0 = __shfl_xor(v0, msk); int pi0 = __shfl_xor(i0, msk);
                float pv1 = __shfl_xor(v1, msk); int pi1 = __shfl_xor(i1, msk);
                ins2(v0, i0, v1, i1, pv0, pi0);
                ins2(v0, i0, v1, i1, pv1, pi1);
            }
            if (tx == 0) {
                part[(size_t)(m0 + row) * gridDim.x + blockIdx.x] =
                    make_float4(v0, __int_as_float(i0), v1, __int_as_float(i1));
            }
        }
        return;
    }

#pragma unroll
    for (int i = 0; i < 8; i++) {
        int m = m0 + ty * 4 + (i < 4 ? i : 60 + i);
#pragma unroll
        for (int jc = 0; jc < 2; jc++) {
            int n = n0 + tx * 4 + jc * 64;
            float4 bb = *(const float4*)&bias[n];
            float4 v;
            v.x = acc[i][jc * 4 + 0] + bb.x;
            v.y = acc[i][jc * 4 + 1] + bb.y;
            v.z = acc[i][jc * 4 + 2] + bb.z;
            v.w = acc[i][jc * 4 + 3] + bb.w;
            if (EPI == 1) {
                v.x = fmaxf(v.x, 0.f); v.y = fmaxf(v.y, 0.f);
                v.z = fmaxf(v.z, 0.f); v.w = fmaxf(v.w, 0.f);
            }
            *(float4*)&C[(size_t)m * N + n] = v;
        }
    }
}

// ---------------------------------------------------------------------------
// reduce 32 per-colblock top-2 candidates -> final top-2 + softmax weights
// ---------------------------------------------------------------------------
__global__ __launch_bounds__(256) void top2_reduce(
    const float4* __restrict__ part, const float* __restrict__ temp_p,
    int2* __restrict__ tki, float2* __restrict__ tkw)
{
    const int tok = blockIdx.x * 256 + threadIdx.x;
    float v0 = -FLT_MAX, v1 = -FLT_MAX; int i0 = 0x7fffffff, i1 = 0x7fffffff;
    const float4* p = part + (size_t)tok * NCB;
    for (int b = 0; b < NCB; b++) {
        float4 q = p[b];
        ins2(v0, i0, v1, i1, q.x, __float_as_int(q.y));
        ins2(v0, i0, v1, i1, q.z, __float_as_int(q.w));
    }
    float tc = fminf(fmaxf(temp_p[0], 0.1f), 5.0f);
    float s0 = fminf(fmaxf(v0 / tc, -10.f), 10.f);
    float s1 = fminf(fmaxf(v1 / tc, -10.f), 10.f);
    float m  = fmaxf(s0, s1);
    float e0 = expf(s0 - m), e1 = expf(s1 - m);
    float inv = 1.0f / (e0 + e1);
    tki[tok] = make_int2(i0, i1);
    tkw[tok] = make_float2(e0 * inv, e1 * inv);
}

// ---------------------------------------------------------------------------
static __device__ inline float blockReduceSum256(float v, float* red) {
#pragma unroll
    for (int off = 32; off; off >>= 1) v += __shfl_down(v, off);
    const int wv = threadIdx.x >> 6;
    if ((threadIdx.x & 63) == 0) red[wv] = v;
    __syncthreads();
    float tot = red[0] + red[1] + red[2] + red[3];
    __syncthreads();
    return tot;
}

// ---------------------------------------------------------------------------
// LN(proj) in place; mix = w0*pool[i0]+w1*pool[i1]; usage atomics
// ---------------------------------------------------------------------------
__global__ __launch_bounds__(256) void build_combined(
    float* __restrict__ proj, float* __restrict__ mix,
    const float* __restrict__ pool,
    const float* __restrict__ gamma, const float* __restrict__ beta,
    const int2* __restrict__ tki, const float2* __restrict__ tkw,
    float* __restrict__ usage)
{
    __shared__ float red[4];
    const int tok = blockIdx.x;
    const int tid = threadIdx.x;
    const int c = tid * 4;

    float4 v = *(const float4*)&proj[(size_t)tok * D_ + c];
    float s = v.x + v.y + v.z + v.w;
    float tot = blockReduceSum256(s, red);
    float mu = tot * (1.0f / D_);
    float d0 = v.x - mu, d1 = v.y - mu, d2 = v.z - mu, d3 = v.w - mu;
    float sq = d0 * d0 + d1 * d1 + d2 * d2 + d3 * d3;
    float var = blockReduceSum256(sq, red) * (1.0f / D_);
    float rs = 1.0f / sqrtf(var + 1e-5f);

    float4 g  = *(const float4*)&gamma[c];
    float4 be = *(const float4*)&beta[c];
    float4 o;
    o.x = d0 * rs * g.x + be.x;
    o.y = d1 * rs * g.y + be.y;
    o.z = d2 * rs * g.z + be.z;
    o.w = d3 * rs * g.w + be.w;
    *(float4*)&proj[(size_t)tok * D_ + c] = o;

    // defensive clamp: a top-2 bug should show as absmax, not a memory fault
    int2   ii = tki[tok];
    int ia = min(max(ii.x, 0), P_ - 1);
    int ib = min(max(ii.y, 0), P_ - 1);
    float2 ww = tkw[tok];
    float4 p0 = *(const float4*)&pool[(size_t)ia * D_ + c];
    float4 p1 = *(const float4*)&pool[(size_t)ib * D_ + c];
    float4 wmv;
    wmv.x = ww.x * p0.x + ww.y * p1.x;
    wmv.y = ww.x * p0.y + ww.y * p1.y;
    wmv.z = ww.x * p0.z + ww.y * p1.z;
    wmv.w = ww.x * p0.w + ww.y * p1.w;
    *(float4*)&mix[(size_t)tok * D_ + c] = wmv;

    if (tid == 0) {
        atomicAdd(&usage[ia], ww.x);
        atomicAdd(&usage[ib], ww.y);
    }
}

// ---------------------------------------------------------------------------
__global__ __launch_bounds__(256) void diversity_kernel(
    const float* __restrict__ usage, float* __restrict__ out)
{
    __shared__ float red[4];
    const int tid = threadIdx.x;
    float s = 0.f;
    for (int j = tid; j < P_; j += 256) s += usage[j];
    float tot = blockReduceSum256(s, red) + 1e-8f;
    float q = 0.f;
    const float uni = 1.0f / P_;
    for (int j = tid; j < P_; j += 256) {
        float f = usage[j] / tot - uni;
        q += f * f;
    }
    float ssq = blockReduceSum256(q, red);
    if (tid == 0) {
        float loss = ssq * (1.0f / P_) * 0.01f;   // scale = min(1, 16.7M/8192) = 1
        out[(size_t)NTOK * D_] = loss;            // f32 output
    }
}

// ---------------------------------------------------------------------------
extern "C" void kernel_launch(void* const* d_in, const int* in_sizes, int n_in,
                              void* d_out, int out_size, void* d_ws, size_t ws_size,
                              hipStream_t stream) {
    const float* x     = (const float*)d_in[0];
    const float* pool  = (const float*)d_in[1];
    // d_in[2] = top_k (hardcoded 2)
    const float* w1    = (const float*)d_in[3];
    const float* b1    = (const float*)d_in[4];
    const float* w2    = (const float*)d_in[5];
    const float* b2    = (const float*)d_in[6];
    const float* temp  = (const float*)d_in[7];
    const float* wp    = (const float*)d_in[8];
    const float* bp    = (const float*)d_in[9];
    const float* gamma = (const float*)d_in[10];
    const float* beta  = (const float*)d_in[11];
    const float* wm    = (const float*)d_in[12];
    const float* bm    = (const float*)d_in[13];
    float* out = (float*)d_out;   // reference output dtype is float32

    // workspace (floats), peak 64.14 MB:
    //   [0, 8M)    inter (GEMM1 out, GEMM2 in) -> proj (GEMM4 out, LN in place)
    //   [8M, 9M)   top2 partials -> mix [8M, 16M) after reduce
    //   [16M, ..)  tki, tkw, usage
    float* ws = (float*)d_ws;
    float*  inter = ws;
    float*  projb = ws;
    float4* partb = (float4*)(ws + (size_t)8 * 1024 * 1024);
    float*  mixb  = ws + (size_t)8 * 1024 * 1024;
    float*  tail  = ws + (size_t)16 * 1024 * 1024;
    int2*   tki   = (int2*)tail;
    float2* tkw   = (float2*)(tail + 16384);
    float*  usage = tail + 32768;

    hipMemsetAsync(usage, 0, P_ * sizeof(float), stream);

    dim3 blk(256);
    // 1) inter = relu(x @ w1 + b1)              [8192 x 1024], K=2048
    gemm_f32<1><<<dim3(I_ / BN, NTOK / BM), blk, 0, stream>>>(
        x, x, H_, H_, w1, b1, inter, nullptr, NTOK, I_, H_);
    // 2) logits GEMM + fused per-colblock top2  [8192 x 4096], K=1024
    gemm_f32<3><<<dim3(P_ / BN, NTOK / BM), blk, 0, stream>>>(
        inter, inter, I_, I_, w2, b2, nullptr, partb, NTOK, P_, I_);
    // 3) reduce partials -> top2 idx + softmax weights
    top2_reduce<<<NTOK / 256, blk, 0, stream>>>(partb, temp, tki, tkw);
    // 4) proj = x @ wp + bp                     [8192 x 1024], K=2048
    gemm_f32<0><<<dim3(D_ / BN, NTOK / BM), blk, 0, stream>>>(
        x, x, H_, H_, wp, bp, projb, nullptr, NTOK, D_, H_);
    // 5) LN in place + mix + usage atomics
    build_combined<<<NTOK, blk, 0, stream>>>(projb, mixb, pool, gamma, beta, tki, tkw, usage);
    // 6) out = [LN(proj), mix] @ wm + bm        [8192 x 1024], K=2048 split@1024, f32 store
    gemm_f32<0><<<dim3(D_ / BN, NTOK / BM), blk, 0, stream>>>(
        projb, mixb, D_, D_, wm, bm, out, nullptr, NTOK, D_, H_);
    // 7) diversity loss scalar (f32)
    diversity_kernel<<<1, blk, 0, stream>>>(usage, out);
}

// Round 5
// 1169.534 us; speedup vs baseline: 1.9412x; 1.9412x over previous
//
#include <hip/hip_runtime.h>
#include <hip/hip_bf16.h>
#include <float.h>
#include <limits.h>

#define NTOK 8192   // B*S
#define H_   2048
#define P_   4096
#define D_   1024
#define I_   1024

#define BM 128
#define BN 128
#define BK 16

#define MAXC  16          // max recheck candidates per token
#define DELTA 0.09375f    // candidate margin (approx-logit worst err ~0.007)

typedef unsigned short ushort_t;
typedef __attribute__((ext_vector_type(8))) short short8;   // 8 bf16 = 4 VGPRs
typedef __attribute__((ext_vector_type(4))) float floatx4;  // MFMA accumulator

static __device__ inline ushort_t f2bf(float f) {
    __hip_bfloat16 h = __float2bfloat16(f);   // RNE
    return *reinterpret_cast<ushort_t*>(&h);
}
static __device__ inline short f2bfs(float f) {
    __hip_bfloat16 h = __float2bfloat16(f);
    return *reinterpret_cast<short*>(&h);
}
static __device__ inline float bf2f(ushort_t s) { return __uint_as_float((unsigned)s << 16); }

static __device__ inline void ins2(float& v0, int& i0, float& v1, int& i1, float v, int i) {
    if (v > v0 || (v == v0 && i < i0)) { v1 = v0; i1 = i0; v0 = v; i0 = i; }
    else if (v > v1 || (v == v1 && i < i1)) { v1 = v; i1 = i; }
}

// ---------------------------------------------------------------------------
// fp32 vector GEMM (EXACT path): inter = relu(x @ w1 + b1), also writes bf16
// copy of inter. 256 thr, 128x128 tile, BK=16, 8x8 micro-tile.
// ---------------------------------------------------------------------------
__global__ __launch_bounds__(256) void gemm_router1(
    const float* __restrict__ A, const float* __restrict__ Bw,
    const float* __restrict__ bias, float* __restrict__ C,
    ushort_t* __restrict__ Cb, int M, int N, int K)
{
    __shared__ float sA[BK][BM];   // k-major
    __shared__ float sB[BK][BN];

    const int tid = threadIdx.x;
    const int m0 = blockIdx.y * BM;
    const int n0 = blockIdx.x * BN;
    const int tx = tid & 15, ty = tid >> 4;

    const int ar = tid >> 1;
    const int ak = (tid & 1) * 8;
    const int brow = tid >> 4;
    const int bcol = (tid & 15) * 8;

    float acc[8][8] = {};

    for (int k0 = 0; k0 < K; k0 += BK) {
        const float* ap = A + (size_t)(m0 + ar) * K + k0 + ak;
        float4 a0 = *(const float4*)ap;
        float4 a1 = *(const float4*)(ap + 4);
        const float* bp = Bw + (size_t)(k0 + brow) * N + n0 + bcol;
        float4 b0 = *(const float4*)bp;
        float4 b1 = *(const float4*)(bp + 4);

        __syncthreads();
        sA[ak + 0][ar] = a0.x; sA[ak + 1][ar] = a0.y;
        sA[ak + 2][ar] = a0.z; sA[ak + 3][ar] = a0.w;
        sA[ak + 4][ar] = a1.x; sA[ak + 5][ar] = a1.y;
        sA[ak + 6][ar] = a1.z; sA[ak + 7][ar] = a1.w;
        *(float4*)&sB[brow][bcol]     = b0;
        *(float4*)&sB[brow][bcol + 4] = b1;
        __syncthreads();

#pragma unroll
        for (int kk = 0; kk < BK; kk++) {
            float4 av0 = *(const float4*)&sA[kk][ty * 4];
            float4 av1 = *(const float4*)&sA[kk][ty * 4 + 64];
            float4 bv0 = *(const float4*)&sB[kk][tx * 4];
            float4 bv1 = *(const float4*)&sB[kk][tx * 4 + 64];
            float a8[8] = {av0.x, av0.y, av0.z, av0.w, av1.x, av1.y, av1.z, av1.w};
            float b8[8] = {bv0.x, bv0.y, bv0.z, bv0.w, bv1.x, bv1.y, bv1.z, bv1.w};
#pragma unroll
            for (int i = 0; i < 8; i++)
#pragma unroll
                for (int j = 0; j < 8; j++) acc[i][j] += a8[i] * b8[j];
        }
    }

#pragma unroll
    for (int i = 0; i < 8; i++) {
        int m = m0 + ty * 4 + (i < 4 ? i : 60 + i);
#pragma unroll
        for (int jc = 0; jc < 2; jc++) {
            int n = n0 + tx * 4 + jc * 64;
            float4 bb = *(const float4*)&bias[n];
            float4 v;
            v.x = fmaxf(acc[i][jc * 4 + 0] + bb.x, 0.f);
            v.y = fmaxf(acc[i][jc * 4 + 1] + bb.y, 0.f);
            v.z = fmaxf(acc[i][jc * 4 + 2] + bb.z, 0.f);
            v.w = fmaxf(acc[i][jc * 4 + 3] + bb.w, 0.f);
            *(float4*)&C[(size_t)m * N + n] = v;
            ushort4 u;
            u.x = f2bf(v.x); u.y = f2bf(v.y); u.z = f2bf(v.z); u.w = f2bf(v.w);
            *(ushort4*)(Cb + (size_t)m * N + n) = u;
        }
    }
}

// ---------------------------------------------------------------------------
// transpose + f32->bf16 convert: in[R][Cc] -> outb[Cc][R] (bf16), optional outf f32
// ---------------------------------------------------------------------------
template<int WRITE_F32>
__global__ __launch_bounds__(256) void transpose_cvt(
    const float* __restrict__ in, int R, int Cc,
    ushort_t* __restrict__ outb, float* __restrict__ outf)
{
    __shared__ float tile[32][33];
    const int tid = threadIdx.x;
    const int c0 = blockIdx.x * 32, r0 = blockIdx.y * 32;
    const int tx = tid & 31, ty = tid >> 5;   // 32 x 8
#pragma unroll
    for (int j = 0; j < 4; j++)
        tile[ty + j * 8][tx] = in[(size_t)(r0 + ty + j * 8) * Cc + c0 + tx];
    __syncthreads();
#pragma unroll
    for (int j = 0; j < 4; j++) {
        float v = tile[tx][ty + j * 8];
        outb[(size_t)(c0 + ty + j * 8) * R + r0 + tx] = f2bf(v);
        if (WRITE_F32) outf[(size_t)(c0 + ty + j * 8) * R + r0 + tx] = v;
    }
}

// ---------------------------------------------------------------------------
// bf16 MFMA GEMM, no LDS (frags streamed from L2/L3):
//   C[M,N] = A[M,K] @ Bt[N,K]^T + bias
// ASRC: 0 = A f32 (convert in-flight), 1 = A bf16
// EPI:  0 = f32 store, 1 = bf16 store
// 256 thr = 4 waves (2x2 of 64x64), 4x4 frags of 16x16x32 per wave.
// Fragment layouts [HW-verified, m89/m120]:
//   A: lane holds A[m = lane&15][k = (lane>>4)*8 + j], j=0..7
//   B: lane holds B[k = (lane>>4)*8 + j][n = lane&15]  (from Bt[n][k] rows)
//   C: reg r   -> C[row = (lane>>4)*4 + r][col = lane&15]
// ---------------------------------------------------------------------------
template<int ASRC, int EPI>
__global__ __launch_bounds__(256) void gemm_mfma(
    const void* __restrict__ Av, int lda,
    const ushort_t* __restrict__ Bt, int ldb,
    const float* __restrict__ bias,
    float* __restrict__ Cf, ushort_t* __restrict__ Cb, int ldc,
    int M, int N, int K)
{
    const int tid  = threadIdx.x;
    const int wave = tid >> 6, lane = tid & 63;
    const int lr = lane & 15, lq = lane >> 4;
    const int m0 = blockIdx.y * 128 + (wave >> 1) * 64;
    const int n0 = blockIdx.x * 128 + (wave & 1) * 64;

    floatx4 acc[4][4] = {};

    for (int k0 = 0; k0 < K; k0 += 32) {
        const int kb = k0 + lq * 8;
        short8 aF[4], bF[4];
#pragma unroll
        for (int f = 0; f < 4; f++) {
            if (ASRC == 1) {
                const ushort_t* ap = (const ushort_t*)Av + (size_t)(m0 + f * 16 + lr) * lda + kb;
                aF[f] = *(const short8*)ap;
            } else {
                const float* ap = (const float*)Av + (size_t)(m0 + f * 16 + lr) * lda + kb;
                float4 a0 = *(const float4*)ap;
                float4 a1 = *(const float4*)(ap + 4);
                short8 t;
                t[0] = f2bfs(a0.x); t[1] = f2bfs(a0.y); t[2] = f2bfs(a0.z); t[3] = f2bfs(a0.w);
                t[4] = f2bfs(a1.x); t[5] = f2bfs(a1.y); t[6] = f2bfs(a1.z); t[7] = f2bfs(a1.w);
                aF[f] = t;
            }
            const ushort_t* bp = Bt + (size_t)(n0 + f * 16 + lr) * ldb + kb;
            bF[f] = *(const short8*)bp;
        }
#pragma unroll
        for (int i = 0; i < 4; i++)
#pragma unroll
            for (int j = 0; j < 4; j++)
                acc[i][j] = __builtin_amdgcn_mfma_f32_16x16x32_bf16(aF[i], bF[j], acc[i][j], 0, 0, 0);
    }

#pragma unroll
    for (int j = 0; j < 4; j++) {
        const int col = n0 + j * 16 + lr;
        const float bv = bias[col];
#pragma unroll
        for (int i = 0; i < 4; i++) {
            const int rowb = m0 + i * 16 + lq * 4;
#pragma unroll
            for (int r = 0; r < 4; r++) {
                float v = acc[i][j][r] + bv;
                if (EPI == 1) Cb[(size_t)(rowb + r) * ldc + col] = f2bf(v);
                else          Cf[(size_t)(rowb + r) * ldc + col] = v;
            }
        }
    }
}

// ---------------------------------------------------------------------------
// per-token: approx top-2 over bf16 logits; emit all indices within DELTA of
// the 2nd max (always includes the approx top-2 themselves), cap MAXC
// ---------------------------------------------------------------------------
__global__ __launch_bounds__(256) void cand_scan(
    const ushort_t* __restrict__ logitsb,
    int* __restrict__ cidx, int* __restrict__ ccnt)
{
    __shared__ float sv0[4], sv1[4];
    __shared__ int   scnt;
    const int tok = blockIdx.x;
    const int tid = threadIdx.x;
    const ushort_t* row = logitsb + (size_t)tok * P_;

    float my[16];
    {
        const uint4* rp = (const uint4*)(row + tid * 16);
        uint4 u0 = rp[0], u1 = rp[1];
        unsigned w[8] = {u0.x, u0.y, u0.z, u0.w, u1.x, u1.y, u1.z, u1.w};
#pragma unroll
        for (int j = 0; j < 8; j++) {
            my[2 * j]     = __uint_as_float(w[j] << 16);
            my[2 * j + 1] = __uint_as_float(w[j] & 0xFFFF0000u);
        }
    }
    float v0 = -FLT_MAX, v1 = -FLT_MAX;
#pragma unroll
    for (int j = 0; j < 16; j++) {
        float v = my[j];
        if (v > v0) { v1 = v0; v0 = v; } else if (v > v1) v1 = v;
    }
#pragma unroll
    for (int off = 1; off < 64; off <<= 1) {
        float u0 = __shfl_xor(v0, off), u1 = __shfl_xor(v1, off);
        float n0 = fmaxf(v0, u0);
        float n1 = fmaxf(fminf(v0, u0), fmaxf(v1, u1));
        v0 = n0; v1 = n1;
    }
    const int wv = tid >> 6;
    if ((tid & 63) == 0) { sv0[wv] = v0; sv1[wv] = v1; }
    if (tid == 0) scnt = 0;
    __syncthreads();
    float g0 = -FLT_MAX, g1 = -FLT_MAX;
#pragma unroll
    for (int w = 0; w < 4; w++) {
        float u0 = sv0[w], u1 = sv1[w];
        float n0 = fmaxf(g0, u0);
        float n1 = fmaxf(fminf(g0, u0), fmaxf(g1, u1));
        g0 = n0; g1 = n1;
    }
    const float thresh = g1 - DELTA;
#pragma unroll
    for (int j = 0; j < 16; j++) {
        if (my[j] >= thresh) {
            int pos = atomicAdd(&scnt, 1);
            if (pos < MAXC) cidx[tok * MAXC + pos] = tid * 16 + j;
        }
    }
    __syncthreads();
    if (tid == 0) ccnt[tok] = min(scnt, MAXC);
}

// ---------------------------------------------------------------------------
// exact f64 recheck of candidate logits -> exact top-2 + softmax weights
// one block per token; wave w handles candidates w, w+4, ...
// ---------------------------------------------------------------------------
__global__ __launch_bounds__(256) void recheck(
    const float* __restrict__ interf, const float* __restrict__ w2tf,
    const float* __restrict__ b2, const int* __restrict__ cidx,
    const int* __restrict__ ccnt, const float* __restrict__ temp_p,
    int2* __restrict__ tki, float2* __restrict__ tkw)
{
    __shared__ double ex[MAXC];
    __shared__ int    sidx[MAXC];
    const int tok  = blockIdx.x;
    const int tid  = threadIdx.x;
    const int wave = tid >> 6, lane = tid & 63;
    int cnt = min(max(ccnt[tok], 0), MAXC);

    const float* ir = interf + (size_t)tok * I_;
    for (int c = wave; c < cnt; c += 4) {
        int p = min(max(cidx[tok * MAXC + c], 0), P_ - 1);
        const float* wr = w2tf + (size_t)p * I_;
        double s = 0.0;
        for (int k = lane; k < I_; k += 64)
            s += (double)ir[k] * (double)wr[k];
#pragma unroll
        for (int off = 32; off; off >>= 1) s += __shfl_down(s, off);
        if (lane == 0) { ex[c] = s + (double)b2[p]; sidx[c] = p; }
    }
    __syncthreads();
    if (tid == 0) {
        float v0 = -FLT_MAX, v1 = -FLT_MAX; int i0 = INT_MAX, i1 = INT_MAX;
        for (int c = 0; c < cnt; c++) ins2(v0, i0, v1, i1, (float)ex[c], sidx[c]);
        if (i0 == INT_MAX) { i0 = 0; v0 = 0.f; }
        if (i1 == INT_MAX) { i1 = i0; v1 = v0; }
        float tc = fminf(fmaxf(temp_p[0], 0.1f), 5.0f);
        float s0 = fminf(fmaxf(v0 / tc, -10.f), 10.f);
        float s1 = fminf(fmaxf(v1 / tc, -10.f), 10.f);
        float m  = fmaxf(s0, s1);
        float e0 = expf(s0 - m), e1 = expf(s1 - m);
        float inv = 1.0f / (e0 + e1);
        tki[tok] = make_int2(i0, i1);
        tkw[tok] = make_float2(e0 * inv, e1 * inv);
    }
}

// ---------------------------------------------------------------------------
static __device__ inline float blockReduceSum256(float v, float* red) {
#pragma unroll
    for (int off = 32; off; off >>= 1) v += __shfl_down(v, off);
    const int wv = threadIdx.x >> 6;
    if ((threadIdx.x & 63) == 0) red[wv] = v;
    __syncthreads();
    float tot = red[0] + red[1] + red[2] + red[3];
    __syncthreads();
    return tot;
}

// ---------------------------------------------------------------------------
// combined(bf16)[tok] = [ LN(proj)*gamma+beta , w0*pool[i0]+w1*pool[i1] ] + usage
// ---------------------------------------------------------------------------
__global__ __launch_bounds__(256) void build_combined(
    const float* __restrict__ proj, ushort_t* __restrict__ comb,
    const float* __restrict__ pool,
    const float* __restrict__ gamma, const float* __restrict__ beta,
    const int2* __restrict__ tki, const float2* __restrict__ tkw,
    float* __restrict__ usage)
{
    __shared__ float red[4];
    const int tok = blockIdx.x;
    const int tid = threadIdx.x;
    const int c = tid * 4;

    float4 v = *(const float4*)&proj[(size_t)tok * D_ + c];
    float s = v.x + v.y + v.z + v.w;
    float tot = blockReduceSum256(s, red);
    float mu = tot * (1.0f / D_);
    float d0 = v.x - mu, d1 = v.y - mu, d2 = v.z - mu, d3 = v.w - mu;
    float sq = d0 * d0 + d1 * d1 + d2 * d2 + d3 * d3;
    float var = blockReduceSum256(sq, red) * (1.0f / D_);
    float rs = 1.0f / sqrtf(var + 1e-5f);

    float4 g  = *(const float4*)&gamma[c];
    float4 be = *(const float4*)&beta[c];
    ushort4 o;
    o.x = f2bf(d0 * rs * g.x + be.x);
    o.y = f2bf(d1 * rs * g.y + be.y);
    o.z = f2bf(d2 * rs * g.z + be.z);
    o.w = f2bf(d3 * rs * g.w + be.w);
    *(ushort4*)&comb[(size_t)tok * (2 * D_) + c] = o;

    int2   ii = tki[tok];
    int ia = min(max(ii.x, 0), P_ - 1);
    int ib = min(max(ii.y, 0), P_ - 1);
    float2 ww = tkw[tok];
    float4 p0 = *(const float4*)&pool[(size_t)ia * D_ + c];
    float4 p1 = *(const float4*)&pool[(size_t)ib * D_ + c];
    ushort4 wm;
    wm.x = f2bf(ww.x * p0.x + ww.y * p1.x);
    wm.y = f2bf(ww.x * p0.y + ww.y * p1.y);
    wm.z = f2bf(ww.x * p0.z + ww.y * p1.z);
    wm.w = f2bf(ww.x * p0.w + ww.y * p1.w);
    *(ushort4*)&comb[(size_t)tok * (2 * D_) + D_ + c] = wm;

    if (tid == 0) {
        atomicAdd(&usage[ia], ww.x);
        atomicAdd(&usage[ib], ww.y);
    }
}

// ---------------------------------------------------------------------------
__global__ __launch_bounds__(256) void diversity_kernel(
    const float* __restrict__ usage, float* __restrict__ out)
{
    __shared__ float red[4];
    const int tid = threadIdx.x;
    float s = 0.f;
    for (int j = tid; j < P_; j += 256) s += usage[j];
    float tot = blockReduceSum256(s, red) + 1e-8f;
    float q = 0.f;
    const float uni = 1.0f / P_;
    for (int j = tid; j < P_; j += 256) {
        float f = usage[j] / tot - uni;
        q += f * f;
    }
    float ssq = blockReduceSum256(q, red);
    if (tid == 0) out[(size_t)NTOK * D_] = ssq * (1.0f / P_) * 0.01f;
}

// ---------------------------------------------------------------------------
extern "C" void kernel_launch(void* const* d_in, const int* in_sizes, int n_in,
                              void* d_out, int out_size, void* d_ws, size_t ws_size,
                              hipStream_t stream) {
    const float* x     = (const float*)d_in[0];
    const float* pool  = (const float*)d_in[1];
    const float* w1    = (const float*)d_in[3];
    const float* b1    = (const float*)d_in[4];
    const float* w2    = (const float*)d_in[5];
    const float* b2    = (const float*)d_in[6];
    const float* temp  = (const float*)d_in[7];
    const float* wp    = (const float*)d_in[8];
    const float* bp    = (const float*)d_in[9];
    const float* gamma = (const float*)d_in[10];
    const float* beta  = (const float*)d_in[11];
    const float* wm    = (const float*)d_in[12];
    const float* bm    = (const float*)d_in[13];
    float* out = (float*)d_out;

    // workspace map (float offsets), peak ~145 MB (round-1 validated >=160 MB):
    //  [0,8M)     interf f32 [8192][1024]
    //  [8M,12M)   interb bf16 [8192][1024]
    //  [12M,28M)  logitsb bf16 [8192][4096]; after cand_scan overlaid by:
    //             proj f32 [8192][1024] @12M, combined bf16 [8192][2048] @20M
    //  [28M,32M)  w2tf f32 [4096][1024]
    //  [32M,34M)  w2t bf16 [4096][1024]
    //  [34M,35M)  wpt bf16 [1024][2048]
    //  [35M,36M)  wmt bf16 [1024][2048]
    //  [36M,...)  cidx int[8192*16], ccnt int[8192], tki, tkw, usage
    float* ws = (float*)d_ws;
    const size_t MF = (size_t)1024 * 1024;
    float*    interf  = ws;
    ushort_t* interb  = (ushort_t*)(ws + 8 * MF);
    ushort_t* logitsb = (ushort_t*)(ws + 12 * MF);
    float*    projb   = ws + 12 * MF;
    ushort_t* comb    = (ushort_t*)(ws + 20 * MF);
    float*    w2tf    = ws + 28 * MF;
    ushort_t* w2t     = (ushort_t*)(ws + 32 * MF);
    ushort_t* wpt     = (ushort_t*)(ws + 34 * MF);
    ushort_t* wmt     = (ushort_t*)(ws + 35 * MF);
    int*      cidx    = (int*)(ws + 36 * MF);
    int*      ccnt    = cidx + NTOK * MAXC;
    int2*     tki     = (int2*)(ccnt + NTOK);
    float2*   tkw     = (float2*)(tki + NTOK);
    float*    usage   = (float*)(tkw + NTOK);

    hipMemsetAsync(usage, 0, P_ * sizeof(float), stream);

    dim3 blk(256);
    // weight transposes + bf16 converts (w2 also kept transposed in f32 for recheck)
    transpose_cvt<1><<<dim3(P_ / 32, I_ / 32), blk, 0, stream>>>(w2, I_, P_, w2t, w2tf);
    transpose_cvt<0><<<dim3(D_ / 32, H_ / 32), blk, 0, stream>>>(wp, H_, D_, wpt, nullptr);
    transpose_cvt<0><<<dim3(D_ / 32, H_ / 32), blk, 0, stream>>>(wm, H_, D_, wmt, nullptr);

    // G1 (EXACT fp32): inter = relu(x@w1+b1), + bf16 copy
    gemm_router1<<<dim3(I_ / BN, NTOK / BM), blk, 0, stream>>>(
        x, w1, b1, interf, interb, NTOK, I_, H_);

    // G2 (MFMA bf16): approx logits (bf16 store)
    gemm_mfma<1, 1><<<dim3(P_ / 128, NTOK / 128), blk, 0, stream>>>(
        interb, I_, w2t, I_, b2, nullptr, logitsb, P_, NTOK, P_, I_);

    // candidate scan + exact f64 recheck -> routing
    cand_scan<<<NTOK, blk, 0, stream>>>(logitsb, cidx, ccnt);
    recheck<<<NTOK, blk, 0, stream>>>(interf, w2tf, b2, cidx, ccnt, temp, tki, tkw);

    // G4 (MFMA, f32 A converted in-flight): proj = x@wp+bp (f32 store, overlays logitsb)
    gemm_mfma<0, 0><<<dim3(D_ / 128, NTOK / 128), blk, 0, stream>>>(
        x, H_, wpt, H_, bp, projb, nullptr, D_, NTOK, D_, H_);

    // LN + pool mix -> combined (bf16) + usage
    build_combined<<<NTOK, blk, 0, stream>>>(projb, comb, pool, gamma, beta, tki, tkw, usage);

    // G6 (MFMA bf16): out = combined@wm+bm (f32 store)
    gemm_mfma<1, 0><<<dim3(D_ / 128, NTOK / 128), blk, 0, stream>>>(
        comb, 2 * D_, wmt, H_, bm, out, nullptr, D_, NTOK, D_, H_);

    diversity_kernel<<<1, blk, 0, stream>>>(usage, out);
}